// Round 1
// baseline (4015.516 us; speedup 1.0000x reference)
//
#include <hip/hip_runtime.h>
#include <math.h>

// LSTMNextWindowPredictor: B=262144 rows, I=13, H=64, T=5, O=13, fp32.
// One thread per row. h-state in LDS (private per thread), c/sigo in VGPRs.
// Weights pre-transposed by prep_kernel into d_ws so the inner k-loop reads
// 64 contiguous wave-uniform dwords -> s_load_dwordx16, v_fmac with SGPR src.

#define TT 5
#define NI 13

// ws layout (float offsets)
#define OFF_WHH 0        // [4][64][64]: ((jc*64+k)*64 + a), a = gate*16+jj
#define OFF_WIH 16384    // [4][13][64]: ((jc*13+i)*64 + a)
#define OFF_B   19712    // [4][64]
#define OFF_W1  19968    // [64][64]: (k*64 + j)
#define OFF_W2  24064    // [64][13]: (k*13 + o)
#define WS_FLOATS 24896

__device__ __forceinline__ float fsig(float v) {
  return __fdividef(1.f, 1.f + __expf(-v));
}
__device__ __forceinline__ float ftanh(float v) {
  return 1.f - __fdividef(2.f, 1.f + __expf(2.f * v));
}

__global__ void prep_kernel(const float* __restrict__ W_ih,
                            const float* __restrict__ W_hh,
                            const float* __restrict__ b_ih,
                            const float* __restrict__ b_hh,
                            const float* __restrict__ W1,
                            const float* __restrict__ W2,
                            float* __restrict__ ws) {
  int idx = blockIdx.x * 256 + threadIdx.x;
  if (idx < 16384) {  // W_hh -> [jc][k][gate*16+jj]
    int jc = idx >> 12, k = (idx >> 6) & 63, a = idx & 63;
    int j = (a >> 4) * 64 + jc * 16 + (a & 15);
    ws[OFF_WHH + idx] = W_hh[j * 64 + k];
  }
  if (idx < 3328) {   // W_ih -> [jc][i][gate*16+jj]
    int jc = idx / 832, r = idx % 832;
    int i = r >> 6, a = r & 63;
    int j = (a >> 4) * 64 + jc * 16 + (a & 15);
    ws[OFF_WIH + idx] = W_ih[j * 13 + i];
  }
  if (idx < 256) {    // combined bias -> [jc][gate*16+jj]
    int jc = idx >> 6, a = idx & 63;
    int j = (a >> 4) * 64 + jc * 16 + (a & 15);
    ws[OFF_B + idx] = b_ih[j] + b_hh[j];
  }
  if (idx < 4096) {   // W1^T -> [k][j]
    int k = idx >> 6, j = idx & 63;
    ws[OFF_W1 + idx] = W1[j * 64 + k];
  }
  if (idx < 832) {    // W2^T -> [k][o]
    int k = idx / 13, o = idx % 13;
    ws[OFF_W2 + idx] = W2[o * 64 + k];
  }
}

__global__ __launch_bounds__(256, 2)
void lstm_kernel(const float* __restrict__ x, const float* __restrict__ ws,
                 const float* __restrict__ b1, const float* __restrict__ b2,
                 float* __restrict__ out) {
  // h state: [k][tid] -> lane-contiguous (2-way bank aliasing = free).
  __shared__ float hbuf[64 * 256];
  const int tid = threadIdx.x;
  const int row = blockIdx.x * 256 + tid;
  const float* __restrict__ xr = x + (size_t)row * (TT * NI);
  const float* __restrict__ whh = ws + OFF_WHH;
  const float* __restrict__ wih = ws + OFF_WIH;
  const float* __restrict__ bias = ws + OFF_B;

  float c[64];
  float sigo[64];
#pragma unroll
  for (int j = 0; j < 64; ++j) {
    c[j] = 0.f;
    hbuf[j * 256 + tid] = 0.f;
  }

#pragma unroll 1
  for (int t = 0; t < TT; ++t) {
    float xt[NI];
#pragma unroll
    for (int i = 0; i < NI; ++i) xt[i] = xr[t * NI + i];

#pragma unroll
    for (int jc = 0; jc < 4; ++jc) {
      float acc[64];
#pragma unroll
      for (int a = 0; a < 64; ++a) acc[a] = bias[jc * 64 + a];

      // x contribution (weights wave-uniform -> SGPR)
#pragma unroll
      for (int i = 0; i < NI; ++i) {
        const float xv = xt[i];
        const float* __restrict__ wr = wih + (jc * NI + i) * 64;
#pragma unroll
        for (int a = 0; a < 64; ++a) acc[a] = fmaf(xv, wr[a], acc[a]);
      }

      // h contribution: rolled k-loop, 64 contiguous uniform weights/iter
#pragma unroll 1
      for (int k = 0; k < 64; ++k) {
        const float hk = hbuf[k * 256 + tid];
        const float* __restrict__ wr = whh + (jc * 64 + k) * 64;
#pragma unroll
        for (int a = 0; a < 64; ++a) acc[a] = fmaf(hk, wr[a], acc[a]);
      }

      // gate epilogue for j = jc*16 + jj; acc layout [gate][jj]
#pragma unroll
      for (int jj = 0; jj < 16; ++jj) {
        const int j = jc * 16 + jj;
        const float si = fsig(acc[jj]);
        const float sf = fsig(acc[16 + jj]);
        const float tg = ftanh(acc[32 + jj]);
        c[j] = fmaf(sf, c[j], si * tg);
        sigo[j] = fsig(acc[48 + jj]);  // defer h write: old h still needed
      }
    }

    // h update (after all chunks consumed old h)
#pragma unroll
    for (int j = 0; j < 64; ++j) {
      hbuf[j * 256 + tid] = sigo[j] * ftanh(c[j]);
    }
  }

  // head: z = relu(h @ W1^T + b1); out = z @ W2^T + b2
  const float* __restrict__ w1 = ws + OFF_W1;
  const float* __restrict__ w2 = ws + OFF_W2;
  {
    float z[64];
#pragma unroll
    for (int a = 0; a < 64; ++a) z[a] = b1[a];
#pragma unroll 1
    for (int k = 0; k < 64; ++k) {
      const float hk = hbuf[k * 256 + tid];
      const float* __restrict__ wr = w1 + k * 64;
#pragma unroll
      for (int a = 0; a < 64; ++a) z[a] = fmaf(hk, wr[a], z[a]);
    }
#pragma unroll
    for (int a = 0; a < 64; ++a) hbuf[a * 256 + tid] = fmaxf(z[a], 0.f);
  }
  {
    float o_[13];
#pragma unroll
    for (int o = 0; o < 13; ++o) o_[o] = b2[o];
#pragma unroll 1
    for (int k = 0; k < 64; ++k) {
      const float zk = hbuf[k * 256 + tid];
      const float* __restrict__ wr = w2 + k * 13;
#pragma unroll
      for (int o = 0; o < 13; ++o) o_[o] = fmaf(zk, wr[o], o_[o]);
    }
    float* __restrict__ orow = out + (size_t)row * 13;
#pragma unroll
    for (int o = 0; o < 13; ++o) orow[o] = o_[o];
  }
}

extern "C" void kernel_launch(void* const* d_in, const int* in_sizes, int n_in,
                              void* d_out, int out_size, void* d_ws, size_t ws_size,
                              hipStream_t stream) {
  const float* x    = (const float*)d_in[0];
  const float* W_ih = (const float*)d_in[1];
  const float* W_hh = (const float*)d_in[2];
  const float* b_ih = (const float*)d_in[3];
  const float* b_hh = (const float*)d_in[4];
  const float* W1   = (const float*)d_in[5];
  const float* b1   = (const float*)d_in[6];
  const float* W2   = (const float*)d_in[7];
  const float* b2   = (const float*)d_in[8];
  float* out = (float*)d_out;
  float* ws  = (float*)d_ws;

  hipLaunchKernelGGL(prep_kernel, dim3(64), dim3(256), 0, stream,
                     W_ih, W_hh, b_ih, b_hh, W1, W2, ws);

  const int B = in_sizes[0] / (TT * NI);  // 262144
  hipLaunchKernelGGL(lstm_kernel, dim3(B / 256), dim3(256), 0, stream,
                     x, ws, b1, b2, out);
}

// Round 2
// 417.351 us; speedup vs baseline: 9.6214x; 9.6214x over previous
//
#include <hip/hip_runtime.h>
#include <math.h>

// LSTMNextWindowPredictor via MFMA: B=262144, I=13, H=64, T=5, O=13, fp32.
// Exact-fp32 GEMMs through bf16 hi/lo split (3-product scheme).
// Per wave: M=32 rows (2 m-tiles of 16). Per t: G[32x256] = X_t[32x13(pad32)]@W_ih^T
//   + H[32x64]@W_hh^T via mfma_f32_16x16x32_bf16, then elementwise LSTM update.
// h round-trips through per-wave LDS (fp32, XOR-swizzled); W_hh-hi frags in LDS.
// LDS = 32768 (whh_hi) + 32768 (h, 4 waves) = 65536 B -> 2 blocks/CU.

#define TT 5
#define NI 13

typedef __attribute__((ext_vector_type(8))) short short8;
typedef __attribute__((ext_vector_type(4))) float f32x4;

// ws byte offsets
#define WHH_HI_OFF 0       // 16384 shorts  [kt2][nt16][lane64][j8]
#define WHH_LO_OFF 32768   // 16384 shorts
#define WIH_HI_OFF 65536   // 4096 shorts   [nt16][lane32][j8] (quads 2,3 aliased)
#define WIH_LO_OFF 73728   // 4096 shorts
#define W1_HI_OFF  81920   // 4096 shorts   [kt2][nt4][lane64][j8]
#define W1_LO_OFF  90112   // 4096 shorts
#define W2_HI_OFF  98304   // 1024 shorts   [kt2][lane64][j8]
#define W2_LO_OFF  100352  // 1024 shorts
#define BIAS_OFF   102400  // 256 floats
// total 103424 bytes

__device__ __forceinline__ short f2bf(float f) {
  unsigned u = __builtin_bit_cast(unsigned, f);
  u = (u + 0x7fffu + ((u >> 16) & 1u)) >> 16;
  return (short)u;
}
__device__ __forceinline__ float bf2f(short s) {
  unsigned u = ((unsigned)(unsigned short)s) << 16;
  return __builtin_bit_cast(float, u);
}
__device__ __forceinline__ float fsig(float v) {
  return __fdividef(1.f, 1.f + __expf(-v));
}
__device__ __forceinline__ float ftanh(float v) {
  return 1.f - __fdividef(2.f, 1.f + __expf(2.f * v));
}

__global__ void prep_kernel(const float* __restrict__ W_ih,
                            const float* __restrict__ W_hh,
                            const float* __restrict__ b_ih,
                            const float* __restrict__ b_hh,
                            const float* __restrict__ W1,
                            const float* __restrict__ W2,
                            short* __restrict__ whh_hi, short* __restrict__ whh_lo,
                            short* __restrict__ wih_hi, short* __restrict__ wih_lo,
                            short* __restrict__ w1_hi,  short* __restrict__ w1_lo,
                            short* __restrict__ w2_hi,  short* __restrict__ w2_lo,
                            float* __restrict__ bias) {
  int idx = blockIdx.x * 256 + threadIdx.x;
  if (idx < 16384) {  // W_hh frags: B[k][n] = W_hh[n*64+k], n = gate*64+hid
    int kt = idx >> 13, r = idx & 8191;
    int nt = r >> 9, lane = (r >> 3) & 63, j = idx & 7;
    int k = kt * 32 + ((lane >> 4) << 3) + j;
    int n = (nt << 4) + (lane & 15);
    float w = W_hh[n * 64 + k];
    short h = f2bf(w);
    whh_hi[idx] = h;
    whh_lo[idx] = f2bf(w - bf2f(h));
  }
  if (idx < 4096) {   // W_ih frags (k 0..15 only; k>=13 zero)
    int nt = idx >> 8, l32 = (idx >> 3) & 31, j = idx & 7;
    int k = ((l32 >> 4) << 3) + j;
    int n = (nt << 4) + (l32 & 15);
    float w = (k < NI) ? W_ih[n * NI + k] : 0.f;
    short h = f2bf(w);
    wih_hi[idx] = h;
    wih_lo[idx] = f2bf(w - bf2f(h));
  }
  if (idx < 4096) {   // W1 frags: B[k][n] = W1[n*64+k]
    int kt = idx >> 11, r = idx & 2047;
    int nt = r >> 9, lane = (r >> 3) & 63, j = idx & 7;
    int k = kt * 32 + ((lane >> 4) << 3) + j;
    int n = (nt << 4) + (lane & 15);
    float w = W1[n * 64 + k];
    short h = f2bf(w);
    w1_hi[idx] = h;
    w1_lo[idx] = f2bf(w - bf2f(h));
  }
  if (idx < 1024) {   // W2 frags: B[k][n] = W2[n*64+k], n>=13 zero
    int kt = idx >> 9, lane = (idx >> 3) & 63, j = idx & 7;
    int k = kt * 32 + ((lane >> 4) << 3) + j;
    int n = lane & 15;
    float w = (n < 13) ? W2[n * 64 + k] : 0.f;
    short h = f2bf(w);
    w2_hi[idx] = h;
    w2_lo[idx] = f2bf(w - bf2f(h));
  }
  if (idx < 256) bias[idx] = b_ih[idx] + b_hh[idx];
}

// read h (fp32, swizzled) from per-wave LDS into bf16 hi/lo A-fragments
__device__ __forceinline__ void read_afrags(const float* __restrict__ hw,
                                            int quad, int mcol,
                                            short8 ah[2][2], short8 al[2][2]) {
#pragma unroll
  for (int mt = 0; mt < 2; ++mt) {
    int m = mt * 16 + mcol;
    int sw = ((m >> 1) & 3) * 8;
#pragma unroll
    for (int kt = 0; kt < 2; ++kt) {
      int off = m * 64 + ((kt * 32 + quad * 8) ^ sw);
      f32x4 f0 = *(const f32x4*)&hw[off];
      f32x4 f1 = *(const f32x4*)&hw[off + 4];
#pragma unroll
      for (int j = 0; j < 4; ++j) {
        short hb = f2bf(f0[j]);
        ah[mt][kt][j] = hb;
        al[mt][kt][j] = f2bf(f0[j] - bf2f(hb));
        short hb2 = f2bf(f1[j]);
        ah[mt][kt][4 + j] = hb2;
        al[mt][kt][4 + j] = f2bf(f1[j] - bf2f(hb2));
      }
    }
  }
}

__global__ __launch_bounds__(256, 1)
void lstm_mfma(const float* __restrict__ x,
               const short* __restrict__ whh_hi_g,
               const short* __restrict__ whh_lo_g,
               const short* __restrict__ wih_hi_g,
               const short* __restrict__ wih_lo_g,
               const short* __restrict__ w1_hi_g,
               const short* __restrict__ w1_lo_g,
               const short* __restrict__ w2_hi_g,
               const short* __restrict__ w2_lo_g,
               const float* __restrict__ biasp,
               const float* __restrict__ b1v,
               const float* __restrict__ b2v,
               float* __restrict__ out) {
  __shared__ __attribute__((aligned(16))) short whh_hi_lds[16384];  // 32 KB
  __shared__ __attribute__((aligned(16))) float hshm[4][2048];      // 32 KB

  const int tid = threadIdx.x;
  const int wave = tid >> 6;
  const int lane = tid & 63;
  const int quad = lane >> 4;
  const int mcol = lane & 15;
  float* __restrict__ hw = &hshm[wave][0];
  const int row0 = blockIdx.x * 128 + wave * 32;

  // stage W_hh hi fragments into LDS (coalesced 16B copies)
  {
    const f32x4* __restrict__ s = (const f32x4*)whh_hi_g;
    f32x4* d = (f32x4*)whh_hi_lds;
#pragma unroll
    for (int i = 0; i < 8; ++i) d[tid + 256 * i] = s[tid + 256 * i];
  }
  __syncthreads();

  float c_st[2][4][4];
#pragma unroll
  for (int mt = 0; mt < 2; ++mt)
#pragma unroll
    for (int jt = 0; jt < 4; ++jt)
#pragma unroll
      for (int r = 0; r < 4; ++r) c_st[mt][jt][r] = 0.f;

  float bias_r[4][4];  // [gate][jt], per-lane col = jt*16+mcol
#pragma unroll
  for (int g = 0; g < 4; ++g)
#pragma unroll
    for (int jt = 0; jt < 4; ++jt)
      bias_r[g][jt] = biasp[((g * 4 + jt) << 4) + mcol];

  const short8* __restrict__ whhlo = (const short8*)whh_lo_g;
  const short8* __restrict__ wihhi = (const short8*)wih_hi_g;
  const short8* __restrict__ wihlo = (const short8*)wih_lo_g;

#pragma unroll 1
  for (int t = 0; t < TT; ++t) {
    // x A-fragments (k 0..12 valid, rest zero)
    short8 xh[2], xl[2];
#pragma unroll
    for (int mt = 0; mt < 2; ++mt) {
      const float* __restrict__ xp =
          x + (size_t)(row0 + mt * 16 + mcol) * (TT * NI) + t * NI;
#pragma unroll
      for (int j = 0; j < 8; ++j) {
        int k = quad * 8 + j;
        float xv = 0.f;
        if (k < NI) xv = xp[k];
        short hb = f2bf(xv);
        xh[mt][j] = hb;
        xl[mt][j] = f2bf(xv - bf2f(hb));
      }
    }

    short8 ah[2][2], al[2][2];
    if (t > 0) read_afrags(hw, quad, mcol, ah, al);

#pragma unroll 1
    for (int jt = 0; jt < 4; ++jt) {
      f32x4 acc[2][4];
#pragma unroll
      for (int mt = 0; mt < 2; ++mt)
#pragma unroll
        for (int g = 0; g < 4; ++g) {
          f32x4 z = {0.f, 0.f, 0.f, 0.f};
          acc[mt][g] = z;
        }

      // x @ W_ih^T (K=32 tile, zeros beyond 13; quads 2,3 alias quads 0,1)
#pragma unroll
      for (int g = 0; g < 4; ++g) {
        int nt = g * 4 + jt;
        short8 bh = wihhi[nt * 32 + (lane & 31)];
        short8 bl = wihlo[nt * 32 + (lane & 31)];
#pragma unroll
        for (int mt = 0; mt < 2; ++mt) {
          acc[mt][g] = __builtin_amdgcn_mfma_f32_16x16x32_bf16(xh[mt], bh, acc[mt][g], 0, 0, 0);
          acc[mt][g] = __builtin_amdgcn_mfma_f32_16x16x32_bf16(xl[mt], bh, acc[mt][g], 0, 0, 0);
          acc[mt][g] = __builtin_amdgcn_mfma_f32_16x16x32_bf16(xh[mt], bl, acc[mt][g], 0, 0, 0);
        }
      }

      // h @ W_hh^T (skip at t=0: h==0)
      if (t > 0) {
#pragma unroll
        for (int kt = 0; kt < 2; ++kt)
#pragma unroll
          for (int g = 0; g < 4; ++g) {
            int fi = (kt * 16 + g * 4 + jt) * 64 + lane;
            short8 bh = *(const short8*)&whh_hi_lds[fi * 8];
            short8 bl = whhlo[fi];
#pragma unroll
            for (int mt = 0; mt < 2; ++mt) {
              acc[mt][g] = __builtin_amdgcn_mfma_f32_16x16x32_bf16(ah[mt][kt], bh, acc[mt][g], 0, 0, 0);
              acc[mt][g] = __builtin_amdgcn_mfma_f32_16x16x32_bf16(al[mt][kt], bh, acc[mt][g], 0, 0, 0);
              acc[mt][g] = __builtin_amdgcn_mfma_f32_16x16x32_bf16(ah[mt][kt], bl, acc[mt][g], 0, 0, 0);
            }
          }
      }

      // elementwise LSTM update; lane owns rows quad*4+reg, col jt*16+mcol
#pragma unroll
      for (int mt = 0; mt < 2; ++mt)
#pragma unroll
        for (int reg = 0; reg < 4; ++reg) {
          float gi = acc[mt][0][reg] + bias_r[0][jt];
          float gf = acc[mt][1][reg] + bias_r[1][jt];
          float gg = acc[mt][2][reg] + bias_r[2][jt];
          float go = acc[mt][3][reg] + bias_r[3][jt];
          float cv = c_st[mt][jt][reg];
          cv = fsig(gf) * cv + fsig(gi) * ftanh(gg);
          c_st[mt][jt][reg] = cv;
          float hn = fsig(go) * ftanh(cv);
          int r = mt * 16 + quad * 4 + reg;
          int jc = jt * 16 + mcol;
          hw[r * 64 + (jc ^ (((r >> 1) & 3) * 8))] = hn;
        }
    }
  }

  // ---- head: z = relu(h @ W1^T + b1) ----
  {
    short8 ah[2][2], al[2][2];
    read_afrags(hw, quad, mcol, ah, al);

    f32x4 zacc[2][4];
#pragma unroll
    for (int mt = 0; mt < 2; ++mt)
#pragma unroll
      for (int nt = 0; nt < 4; ++nt) {
        f32x4 z = {0.f, 0.f, 0.f, 0.f};
        zacc[mt][nt] = z;
      }
#pragma unroll
    for (int kt = 0; kt < 2; ++kt)
#pragma unroll
      for (int nt = 0; nt < 4; ++nt) {
        int fi = (kt * 4 + nt) * 64 + lane;
        short8 bh = ((const short8*)w1_hi_g)[fi];
        short8 bl = ((const short8*)w1_lo_g)[fi];
#pragma unroll
        for (int mt = 0; mt < 2; ++mt) {
          zacc[mt][nt] = __builtin_amdgcn_mfma_f32_16x16x32_bf16(ah[mt][kt], bh, zacc[mt][nt], 0, 0, 0);
          zacc[mt][nt] = __builtin_amdgcn_mfma_f32_16x16x32_bf16(al[mt][kt], bh, zacc[mt][nt], 0, 0, 0);
          zacc[mt][nt] = __builtin_amdgcn_mfma_f32_16x16x32_bf16(ah[mt][kt], bl, zacc[mt][nt], 0, 0, 0);
        }
      }
    float b1_r[4];
#pragma unroll
    for (int nt = 0; nt < 4; ++nt) b1_r[nt] = b1v[nt * 16 + mcol];
#pragma unroll
    for (int mt = 0; mt < 2; ++mt)
#pragma unroll
      for (int nt = 0; nt < 4; ++nt)
#pragma unroll
        for (int reg = 0; reg < 4; ++reg) {
          float zv = fmaxf(zacc[mt][nt][reg] + b1_r[nt], 0.f);
          int r = mt * 16 + quad * 4 + reg;
          int jc = nt * 16 + mcol;
          hw[r * 64 + (jc ^ (((r >> 1) & 3) * 8))] = zv;
        }
  }

  // ---- head: out = z @ W2^T + b2 ----
  {
    short8 zh[2][2], zl[2][2];
    read_afrags(hw, quad, mcol, zh, zl);

    f32x4 oacc[2];
#pragma unroll
    for (int mt = 0; mt < 2; ++mt) {
      f32x4 z = {0.f, 0.f, 0.f, 0.f};
      oacc[mt] = z;
    }
#pragma unroll
    for (int kt = 0; kt < 2; ++kt) {
      int fi = kt * 64 + lane;
      short8 bh = ((const short8*)w2_hi_g)[fi];
      short8 bl = ((const short8*)w2_lo_g)[fi];
#pragma unroll
      for (int mt = 0; mt < 2; ++mt) {
        oacc[mt] = __builtin_amdgcn_mfma_f32_16x16x32_bf16(zh[mt][kt], bh, oacc[mt], 0, 0, 0);
        oacc[mt] = __builtin_amdgcn_mfma_f32_16x16x32_bf16(zl[mt][kt], bh, oacc[mt], 0, 0, 0);
        oacc[mt] = __builtin_amdgcn_mfma_f32_16x16x32_bf16(zh[mt][kt], bl, oacc[mt], 0, 0, 0);
      }
    }
    float b2r = (mcol < 13) ? b2v[mcol] : 0.f;
    if (mcol < 13) {
#pragma unroll
      for (int mt = 0; mt < 2; ++mt)
#pragma unroll
        for (int reg = 0; reg < 4; ++reg) {
          int row = row0 + mt * 16 + quad * 4 + reg;
          out[row * 13 + mcol] = oacc[mt][reg] + b2r;
        }
    }
  }
}

extern "C" void kernel_launch(void* const* d_in, const int* in_sizes, int n_in,
                              void* d_out, int out_size, void* d_ws, size_t ws_size,
                              hipStream_t stream) {
  const float* x    = (const float*)d_in[0];
  const float* W_ih = (const float*)d_in[1];
  const float* W_hh = (const float*)d_in[2];
  const float* b_ih = (const float*)d_in[3];
  const float* b_hh = (const float*)d_in[4];
  const float* W1   = (const float*)d_in[5];
  const float* b1   = (const float*)d_in[6];
  const float* W2   = (const float*)d_in[7];
  const float* b2   = (const float*)d_in[8];
  float* out = (float*)d_out;
  char* ws = (char*)d_ws;

  short* whh_hi = (short*)(ws + WHH_HI_OFF);
  short* whh_lo = (short*)(ws + WHH_LO_OFF);
  short* wih_hi = (short*)(ws + WIH_HI_OFF);
  short* wih_lo = (short*)(ws + WIH_LO_OFF);
  short* w1_hi  = (short*)(ws + W1_HI_OFF);
  short* w1_lo  = (short*)(ws + W1_LO_OFF);
  short* w2_hi  = (short*)(ws + W2_HI_OFF);
  short* w2_lo  = (short*)(ws + W2_LO_OFF);
  float* bias   = (float*)(ws + BIAS_OFF);

  hipLaunchKernelGGL(prep_kernel, dim3(64), dim3(256), 0, stream,
                     W_ih, W_hh, b_ih, b_hh, W1, W2,
                     whh_hi, whh_lo, wih_hi, wih_lo, w1_hi, w1_lo, w2_hi, w2_lo, bias);

  const int B = in_sizes[0] / (TT * NI);  // 262144
  hipLaunchKernelGGL(lstm_mfma, dim3(B / 128), dim3(256), 0, stream,
                     x, whh_hi, whh_lo, wih_hi, wih_lo, w1_hi, w1_lo,
                     w2_hi, w2_lo, bias, b1, b2, out);
}

// Round 3
// 357.333 us; speedup vs baseline: 11.2375x; 1.1680x over previous
//
#include <hip/hip_runtime.h>
#include <math.h>

// LSTMNextWindowPredictor via fp16 single-product MFMA: B=262144, I=13, H=64,
// T=5, O=13, fp32 in/out. Per wave: M=32 rows. Per t:
//   G[32x256] = X_t[32x13(pad32)] @ W_ih^T + H[32x64] @ W_hh^T
// via mfma_f32_16x16x32_f16 (fp32 accumulate), then elementwise LSTM update.
// h lives per-wave in LDS as fp16 in A-fragment k-contiguous layout (XOR
// swizzled by row&7) -> A-frag loads are pure ds_read_b128, no conversion.
// W_hh fp16 frags staged in LDS (32 KB). LDS total 48 KB -> 3 blocks/CU.
// Numerics: fp16 quantization ~1e-3 + fast transcendentals ~1e-3, threshold 4.28e-3.

#define TT 5
#define NI 13

typedef _Float16 half8 __attribute__((ext_vector_type(8)));
typedef __attribute__((ext_vector_type(4))) float f32x4;

// ws byte offsets
#define WHH_OFF  0       // 16384 halves [kt2][nt16][lane64][j8]  (32 KB)
#define WIH_OFF  32768   // 4096 halves  [nt16][l32][j8] (quads 2,3 alias; A-side zeros cover)
#define W1_OFF   40960   // 4096 halves  [kt2][nt4][lane64][j8]
#define W2_OFF   49152   // 1024 halves  [kt2][lane64][j8] (n>=13 zero)
#define BIAS_OFF 51200   // 256 floats (b_ih + b_hh)

__device__ __forceinline__ float fsig(float v) {
  return __fdividef(1.f, 1.f + __expf(-v));
}
__device__ __forceinline__ float ftanh(float v) {
  return 1.f - __fdividef(2.f, 1.f + __expf(2.f * v));
}

__global__ void prep_kernel(const float* __restrict__ W_ih,
                            const float* __restrict__ W_hh,
                            const float* __restrict__ b_ih,
                            const float* __restrict__ b_hh,
                            const float* __restrict__ W1,
                            const float* __restrict__ W2,
                            _Float16* __restrict__ whh,
                            _Float16* __restrict__ wih,
                            _Float16* __restrict__ w1,
                            _Float16* __restrict__ w2,
                            float* __restrict__ bias) {
  int idx = blockIdx.x * 256 + threadIdx.x;
  if (idx < 16384) {  // W_hh B-frags: B[k][n] = W_hh[n*64+k]
    int kt = idx >> 13, r = idx & 8191;
    int nt = r >> 9, lane = (r >> 3) & 63, j = idx & 7;
    int k = kt * 32 + ((lane >> 4) << 3) + j;
    int n = (nt << 4) + (lane & 15);
    whh[idx] = (_Float16)W_hh[n * 64 + k];
  }
  if (idx < 4096) {   // W_ih B-frags, k tile of 32 (k>=13 zero)
    int nt = idx >> 8, l32 = (idx >> 3) & 31, j = idx & 7;
    int k = ((l32 >> 4) << 3) + j;
    int n = (nt << 4) + (l32 & 15);
    wih[idx] = (_Float16)((k < NI) ? W_ih[n * NI + k] : 0.f);
  }
  if (idx < 4096) {   // W1 B-frags: B[k][n] = W1[n*64+k]
    int kt = idx >> 11, r = idx & 2047;
    int nt = r >> 9, lane = (r >> 3) & 63, j = idx & 7;
    int k = kt * 32 + ((lane >> 4) << 3) + j;
    int n = (nt << 4) + (lane & 15);
    w1[idx] = (_Float16)W1[n * 64 + k];
  }
  if (idx < 1024) {   // W2 B-frags (n>=13 zero)
    int kt = idx >> 9, lane = (idx >> 3) & 63, j = idx & 7;
    int k = kt * 32 + ((lane >> 4) << 3) + j;
    int n = lane & 15;
    w2[idx] = (_Float16)((n < 13) ? W2[n * 64 + k] : 0.f);
  }
  if (idx < 256) bias[idx] = b_ih[idx] + b_hh[idx];
}

// Read A-fragments (rows mt*16+mcol, k = kt*32+quad*8+j) from swizzled fp16 LDS.
__device__ __forceinline__ void read_afrags(const _Float16* __restrict__ hw,
                                            int quad, int mcol, half8 a[2][2]) {
#pragma unroll
  for (int mt = 0; mt < 2; ++mt) {
    const int r = mt * 16 + mcol;
#pragma unroll
    for (int kt = 0; kt < 2; ++kt) {
      const int blk = (kt * 4 + quad) ^ (r & 7);
      a[mt][kt] = *(const half8*)&hw[r * 64 + blk * 8];
    }
  }
}

__global__ __launch_bounds__(256, 3)
void lstm_mfma(const float* __restrict__ x,
               const _Float16* __restrict__ whh_g,
               const _Float16* __restrict__ wih_g,
               const _Float16* __restrict__ w1_g,
               const _Float16* __restrict__ w2_g,
               const float* __restrict__ biasp,
               const float* __restrict__ b1v,
               const float* __restrict__ b2v,
               float* __restrict__ out) {
  __shared__ __attribute__((aligned(16))) _Float16 whh_lds[16384];  // 32 KB
  __shared__ __attribute__((aligned(16))) _Float16 hshm[4][2048];   // 16 KB

  const int tid = threadIdx.x;
  const int wave = tid >> 6;
  const int lane = tid & 63;
  const int quad = lane >> 4;
  const int mcol = lane & 15;
  _Float16* __restrict__ hw = &hshm[wave][0];
  const int row0 = blockIdx.x * 128 + wave * 32;

  // stage W_hh fragments into LDS (one-time, coalesced 16B)
  {
    const f32x4* __restrict__ s = (const f32x4*)whh_g;
    f32x4* d = (f32x4*)whh_lds;
#pragma unroll
    for (int i = 0; i < 8; ++i) d[tid + 256 * i] = s[tid + 256 * i];
  }
  __syncthreads();

  float c_st[2][4][4];
#pragma unroll
  for (int mt = 0; mt < 2; ++mt)
#pragma unroll
    for (int jt = 0; jt < 4; ++jt)
#pragma unroll
      for (int r = 0; r < 4; ++r) c_st[mt][jt][r] = 0.f;

  float bias_r[4][4];  // [g][jt]: per-lane col = (g*4+jt)*16 + mcol
#pragma unroll
  for (int g = 0; g < 4; ++g)
#pragma unroll
    for (int jt = 0; jt < 4; ++jt)
      bias_r[g][jt] = biasp[((g * 4 + jt) << 4) + mcol];

  const half8* __restrict__ wihf = (const half8*)wih_g;
  const half8* __restrict__ whhf = (const half8*)whh_lds;

#pragma unroll 1
  for (int t = 0; t < TT; ++t) {
    // x A-fragments (k = quad*8+j, zero beyond 12)
    half8 xa[2];
#pragma unroll
    for (int mt = 0; mt < 2; ++mt) {
      const float* __restrict__ xp =
          x + (size_t)(row0 + mt * 16 + mcol) * (TT * NI) + t * NI;
#pragma unroll
      for (int j = 0; j < 8; ++j) {
        const int k = quad * 8 + j;
        xa[mt][j] = (_Float16)((k < NI) ? xp[k] : 0.f);
      }
    }

    half8 ah[2][2];
    if (t > 0) read_afrags(hw, quad, mcol, ah);

#pragma unroll 1
    for (int jt = 0; jt < 4; ++jt) {
      f32x4 acc[2][4];
#pragma unroll
      for (int mt = 0; mt < 2; ++mt)
#pragma unroll
        for (int g = 0; g < 4; ++g) {
          const float b = bias_r[g][jt];
          f32x4 z = {b, b, b, b};
          acc[mt][g] = z;
        }

      // x @ W_ih^T
#pragma unroll
      for (int g = 0; g < 4; ++g) {
        const half8 bfr = wihf[(g * 4 + jt) * 32 + (lane & 31)];
#pragma unroll
        for (int mt = 0; mt < 2; ++mt)
          acc[mt][g] = __builtin_amdgcn_mfma_f32_16x16x32_f16(xa[mt], bfr, acc[mt][g], 0, 0, 0);
      }

      // h @ W_hh^T (h==0 at t=0)
      if (t > 0) {
#pragma unroll
        for (int kt = 0; kt < 2; ++kt)
#pragma unroll
          for (int g = 0; g < 4; ++g) {
            const half8 bfr = whhf[(kt * 16 + g * 4 + jt) * 64 + lane];
#pragma unroll
            for (int mt = 0; mt < 2; ++mt)
              acc[mt][g] = __builtin_amdgcn_mfma_f32_16x16x32_f16(ah[mt][kt], bfr, acc[mt][g], 0, 0, 0);
          }
      }

      // elementwise LSTM update; lane owns rows quad*4+reg, col jt*16+mcol
#pragma unroll
      for (int mt = 0; mt < 2; ++mt)
#pragma unroll
        for (int reg = 0; reg < 4; ++reg) {
          const float gi = acc[mt][0][reg];
          const float gf = acc[mt][1][reg];
          const float gg = acc[mt][2][reg];
          const float go = acc[mt][3][reg];
          float cv = c_st[mt][jt][reg];
          cv = fsig(gf) * cv + fsig(gi) * ftanh(gg);
          c_st[mt][jt][reg] = cv;
          const float hn = fsig(go) * ftanh(cv);
          const int r = mt * 16 + quad * 4 + reg;
          const int k = jt * 16 + mcol;
          hw[r * 64 + (((k >> 3) ^ (r & 7)) << 3) + (k & 7)] = (_Float16)hn;
        }
    }
  }

  // ---- head: z = relu(h @ W1^T + b1), fp16 round-trip through LDS ----
  {
    half8 ah[2][2];
    read_afrags(hw, quad, mcol, ah);

    f32x4 zacc[2][4];
#pragma unroll
    for (int nt = 0; nt < 4; ++nt) {
      const float b = b1v[nt * 16 + mcol];
#pragma unroll
      for (int mt = 0; mt < 2; ++mt) {
        f32x4 z = {b, b, b, b};
        zacc[mt][nt] = z;
      }
    }
#pragma unroll
    for (int kt = 0; kt < 2; ++kt)
#pragma unroll
      for (int nt = 0; nt < 4; ++nt) {
        const half8 bfr = ((const half8*)w1_g)[(kt * 4 + nt) * 64 + lane];
#pragma unroll
        for (int mt = 0; mt < 2; ++mt)
          zacc[mt][nt] = __builtin_amdgcn_mfma_f32_16x16x32_f16(ah[mt][kt], bfr, zacc[mt][nt], 0, 0, 0);
      }
#pragma unroll
    for (int mt = 0; mt < 2; ++mt)
#pragma unroll
      for (int nt = 0; nt < 4; ++nt)
#pragma unroll
        for (int reg = 0; reg < 4; ++reg) {
          const float zv = fmaxf(zacc[mt][nt][reg], 0.f);
          const int r = mt * 16 + quad * 4 + reg;
          const int k = nt * 16 + mcol;
          hw[r * 64 + (((k >> 3) ^ (r & 7)) << 3) + (k & 7)] = (_Float16)zv;
        }
  }

  // ---- head: out = z @ W2^T + b2 ----
  {
    half8 zh[2][2];
    read_afrags(hw, quad, mcol, zh);

    const float b2r = (mcol < 13) ? b2v[mcol] : 0.f;
    f32x4 oacc[2];
#pragma unroll
    for (int mt = 0; mt < 2; ++mt) {
      f32x4 z = {b2r, b2r, b2r, b2r};
      oacc[mt] = z;
    }
#pragma unroll
    for (int kt = 0; kt < 2; ++kt) {
      const half8 bfr = ((const half8*)w2_g)[kt * 64 + lane];
#pragma unroll
      for (int mt = 0; mt < 2; ++mt)
        oacc[mt] = __builtin_amdgcn_mfma_f32_16x16x32_f16(zh[mt][kt], bfr, oacc[mt], 0, 0, 0);
    }
    if (mcol < 13) {
#pragma unroll
      for (int mt = 0; mt < 2; ++mt)
#pragma unroll
        for (int reg = 0; reg < 4; ++reg) {
          const int row = row0 + mt * 16 + quad * 4 + reg;
          out[row * 13 + mcol] = oacc[mt][reg];
        }
    }
  }
}

extern "C" void kernel_launch(void* const* d_in, const int* in_sizes, int n_in,
                              void* d_out, int out_size, void* d_ws, size_t ws_size,
                              hipStream_t stream) {
  const float* x    = (const float*)d_in[0];
  const float* W_ih = (const float*)d_in[1];
  const float* W_hh = (const float*)d_in[2];
  const float* b_ih = (const float*)d_in[3];
  const float* b_hh = (const float*)d_in[4];
  const float* W1   = (const float*)d_in[5];
  const float* b1   = (const float*)d_in[6];
  const float* W2   = (const float*)d_in[7];
  const float* b2   = (const float*)d_in[8];
  float* out = (float*)d_out;
  char* ws = (char*)d_ws;

  _Float16* whh = (_Float16*)(ws + WHH_OFF);
  _Float16* wih = (_Float16*)(ws + WIH_OFF);
  _Float16* w1  = (_Float16*)(ws + W1_OFF);
  _Float16* w2  = (_Float16*)(ws + W2_OFF);
  float* bias   = (float*)(ws + BIAS_OFF);

  hipLaunchKernelGGL(prep_kernel, dim3(64), dim3(256), 0, stream,
                     W_ih, W_hh, b_ih, b_hh, W1, W2, whh, wih, w1, w2, bias);

  const int B = in_sizes[0] / (TT * NI);  // 262144
  hipLaunchKernelGGL(lstm_mfma, dim3(B / 128), dim3(256), 0, stream,
                     x, whh, wih, w1, w2, bias, b1, b2, out);
}

// Round 4
// 272.109 us; speedup vs baseline: 14.7570x; 1.3132x over previous
//
#include <hip/hip_runtime.h>
#include <math.h>

// LSTMNextWindowPredictor via fp16 single-product MFMA: B=262144, I=13, H=64,
// T=5, O=13, fp32 in/out. Per wave: M=32 rows. Per t:
//   G[32x256] = X_t[32x13(pad32)] @ W_ih^T + H[32x64] @ W_hh^T
// via mfma_f32_16x16x32_f16 (fp32 accumulate), then elementwise LSTM update.
// h lives per-wave in LDS as fp16 in A-fragment k-contiguous layout (XOR
// swizzled by row&7) -> A-frag loads are pure ds_read_b128, no conversion.
// W_hh fp16 frags staged in LDS (32 KB). LDS total 48 KB -> 3 blocks/CU.
// R4: sigmoid/tanh via v_exp_f32 + v_rcp_f32 hardware ops (__fdividef was
// lowering to the full IEEE div sequence ~10 VALU ops -> VALUBusy 76%).

#define TT 5
#define NI 13

typedef _Float16 half8 __attribute__((ext_vector_type(8)));
typedef __attribute__((ext_vector_type(4))) float f32x4;

// ws byte offsets
#define WHH_OFF  0       // 16384 halves [kt2][nt16][lane64][j8]  (32 KB)
#define WIH_OFF  32768   // 4096 halves  [nt16][l32][j8] (quads 2,3 alias; A-side zeros cover)
#define W1_OFF   40960   // 4096 halves  [kt2][nt4][lane64][j8]
#define W2_OFF   49152   // 1024 halves  [kt2][lane64][j8] (n>=13 zero)
#define BIAS_OFF 51200   // 256 floats (b_ih + b_hh)

#define LOG2E 1.44269504088896340736f

__device__ __forceinline__ float fexp(float v) {  // e^v via v_exp_f32 (2^x)
  return __builtin_amdgcn_exp2f(v * LOG2E);
}
__device__ __forceinline__ float fsig(float v) {  // 1/(1+e^-v), v_rcp_f32
  return __builtin_amdgcn_rcpf(1.f + fexp(-v));
}
__device__ __forceinline__ float ftanh(float v) { // 1 - 2/(1+e^{2v})
  return fmaf(-2.f, __builtin_amdgcn_rcpf(1.f + fexp(2.f * v)), 1.f);
}

__global__ void prep_kernel(const float* __restrict__ W_ih,
                            const float* __restrict__ W_hh,
                            const float* __restrict__ b_ih,
                            const float* __restrict__ b_hh,
                            const float* __restrict__ W1,
                            const float* __restrict__ W2,
                            _Float16* __restrict__ whh,
                            _Float16* __restrict__ wih,
                            _Float16* __restrict__ w1,
                            _Float16* __restrict__ w2,
                            float* __restrict__ bias) {
  int idx = blockIdx.x * 256 + threadIdx.x;
  if (idx < 16384) {  // W_hh B-frags: B[k][n] = W_hh[n*64+k]
    int kt = idx >> 13, r = idx & 8191;
    int nt = r >> 9, lane = (r >> 3) & 63, j = idx & 7;
    int k = kt * 32 + ((lane >> 4) << 3) + j;
    int n = (nt << 4) + (lane & 15);
    whh[idx] = (_Float16)W_hh[n * 64 + k];
  }
  if (idx < 4096) {   // W_ih B-frags, k tile of 32 (k>=13 zero)
    int nt = idx >> 8, l32 = (idx >> 3) & 31, j = idx & 7;
    int k = ((l32 >> 4) << 3) + j;
    int n = (nt << 4) + (l32 & 15);
    wih[idx] = (_Float16)((k < NI) ? W_ih[n * NI + k] : 0.f);
  }
  if (idx < 4096) {   // W1 B-frags: B[k][n] = W1[n*64+k]
    int kt = idx >> 11, r = idx & 2047;
    int nt = r >> 9, lane = (r >> 3) & 63, j = idx & 7;
    int k = kt * 32 + ((lane >> 4) << 3) + j;
    int n = (nt << 4) + (lane & 15);
    w1[idx] = (_Float16)W1[n * 64 + k];
  }
  if (idx < 1024) {   // W2 B-frags (n>=13 zero)
    int kt = idx >> 9, lane = (idx >> 3) & 63, j = idx & 7;
    int k = kt * 32 + ((lane >> 4) << 3) + j;
    int n = lane & 15;
    w2[idx] = (_Float16)((n < 13) ? W2[n * 64 + k] : 0.f);
  }
  if (idx < 256) bias[idx] = b_ih[idx] + b_hh[idx];
}

// Read A-fragments (rows mt*16+mcol, k = kt*32+quad*8+j) from swizzled fp16 LDS.
__device__ __forceinline__ void read_afrags(const _Float16* __restrict__ hw,
                                            int quad, int mcol, half8 a[2][2]) {
#pragma unroll
  for (int mt = 0; mt < 2; ++mt) {
    const int r = mt * 16 + mcol;
#pragma unroll
    for (int kt = 0; kt < 2; ++kt) {
      const int blk = (kt * 4 + quad) ^ (r & 7);
      a[mt][kt] = *(const half8*)&hw[r * 64 + blk * 8];
    }
  }
}

__global__ __launch_bounds__(256, 3)
void lstm_mfma(const float* __restrict__ x,
               const _Float16* __restrict__ whh_g,
               const _Float16* __restrict__ wih_g,
               const _Float16* __restrict__ w1_g,
               const _Float16* __restrict__ w2_g,
               const float* __restrict__ biasp,
               const float* __restrict__ b1v,
               const float* __restrict__ b2v,
               float* __restrict__ out) {
  __shared__ __attribute__((aligned(16))) _Float16 whh_lds[16384];  // 32 KB
  __shared__ __attribute__((aligned(16))) _Float16 hshm[4][2048];   // 16 KB

  const int tid = threadIdx.x;
  const int wave = tid >> 6;
  const int lane = tid & 63;
  const int quad = lane >> 4;
  const int mcol = lane & 15;
  _Float16* __restrict__ hw = &hshm[wave][0];
  const int row0 = blockIdx.x * 128 + wave * 32;

  // stage W_hh fragments into LDS (one-time, coalesced 16B)
  {
    const f32x4* __restrict__ s = (const f32x4*)whh_g;
    f32x4* d = (f32x4*)whh_lds;
#pragma unroll
    for (int i = 0; i < 8; ++i) d[tid + 256 * i] = s[tid + 256 * i];
  }
  __syncthreads();

  float c_st[2][4][4];
#pragma unroll
  for (int mt = 0; mt < 2; ++mt)
#pragma unroll
    for (int jt = 0; jt < 4; ++jt)
#pragma unroll
      for (int r = 0; r < 4; ++r) c_st[mt][jt][r] = 0.f;

  float bias_r[4][4];  // [g][jt]: per-lane col = (g*4+jt)*16 + mcol
#pragma unroll
  for (int g = 0; g < 4; ++g)
#pragma unroll
    for (int jt = 0; jt < 4; ++jt)
      bias_r[g][jt] = biasp[((g * 4 + jt) << 4) + mcol];

  const half8* __restrict__ wihf = (const half8*)wih_g;
  const half8* __restrict__ whhf = (const half8*)whh_lds;

#pragma unroll 1
  for (int t = 0; t < TT; ++t) {
    // x A-fragments (k = quad*8+j, zero beyond 12)
    half8 xa[2];
#pragma unroll
    for (int mt = 0; mt < 2; ++mt) {
      const float* __restrict__ xp =
          x + (size_t)(row0 + mt * 16 + mcol) * (TT * NI) + t * NI;
#pragma unroll
      for (int j = 0; j < 8; ++j) {
        const int k = quad * 8 + j;
        xa[mt][j] = (_Float16)((k < NI) ? xp[k] : 0.f);
      }
    }

    half8 ah[2][2];
    if (t > 0) read_afrags(hw, quad, mcol, ah);

#pragma unroll 1
    for (int jt = 0; jt < 4; ++jt) {
      f32x4 acc[2][4];
#pragma unroll
      for (int mt = 0; mt < 2; ++mt)
#pragma unroll
        for (int g = 0; g < 4; ++g) {
          const float b = bias_r[g][jt];
          f32x4 z = {b, b, b, b};
          acc[mt][g] = z;
        }

      // x @ W_ih^T
#pragma unroll
      for (int g = 0; g < 4; ++g) {
        const half8 bfr = wihf[(g * 4 + jt) * 32 + (lane & 31)];
#pragma unroll
        for (int mt = 0; mt < 2; ++mt)
          acc[mt][g] = __builtin_amdgcn_mfma_f32_16x16x32_f16(xa[mt], bfr, acc[mt][g], 0, 0, 0);
      }

      // h @ W_hh^T (h==0 at t=0)
      if (t > 0) {
#pragma unroll
        for (int kt = 0; kt < 2; ++kt)
#pragma unroll
          for (int g = 0; g < 4; ++g) {
            const half8 bfr = whhf[(kt * 16 + g * 4 + jt) * 64 + lane];
#pragma unroll
            for (int mt = 0; mt < 2; ++mt)
              acc[mt][g] = __builtin_amdgcn_mfma_f32_16x16x32_f16(ah[mt][kt], bfr, acc[mt][g], 0, 0, 0);
          }
      }

      // elementwise LSTM update; lane owns rows quad*4+reg, col jt*16+mcol
#pragma unroll
      for (int mt = 0; mt < 2; ++mt)
#pragma unroll
        for (int reg = 0; reg < 4; ++reg) {
          const float gi = acc[mt][0][reg];
          const float gf = acc[mt][1][reg];
          const float gg = acc[mt][2][reg];
          const float go = acc[mt][3][reg];
          float cv = c_st[mt][jt][reg];
          cv = fsig(gf) * cv + fsig(gi) * ftanh(gg);
          c_st[mt][jt][reg] = cv;
          const float hn = fsig(go) * ftanh(cv);
          const int r = mt * 16 + quad * 4 + reg;
          const int k = jt * 16 + mcol;
          hw[r * 64 + (((k >> 3) ^ (r & 7)) << 3) + (k & 7)] = (_Float16)hn;
        }
    }
  }

  // ---- head: z = relu(h @ W1^T + b1), fp16 round-trip through LDS ----
  {
    half8 ah[2][2];
    read_afrags(hw, quad, mcol, ah);

    f32x4 zacc[2][4];
#pragma unroll
    for (int nt = 0; nt < 4; ++nt) {
      const float b = b1v[nt * 16 + mcol];
#pragma unroll
      for (int mt = 0; mt < 2; ++mt) {
        f32x4 z = {b, b, b, b};
        zacc[mt][nt] = z;
      }
    }
#pragma unroll
    for (int kt = 0; kt < 2; ++kt)
#pragma unroll
      for (int nt = 0; nt < 4; ++nt) {
        const half8 bfr = ((const half8*)w1_g)[(kt * 4 + nt) * 64 + lane];
#pragma unroll
        for (int mt = 0; mt < 2; ++mt)
          zacc[mt][nt] = __builtin_amdgcn_mfma_f32_16x16x32_f16(ah[mt][kt], bfr, zacc[mt][nt], 0, 0, 0);
      }
#pragma unroll
    for (int mt = 0; mt < 2; ++mt)
#pragma unroll
      for (int nt = 0; nt < 4; ++nt)
#pragma unroll
        for (int reg = 0; reg < 4; ++reg) {
          const float zv = fmaxf(zacc[mt][nt][reg], 0.f);
          const int r = mt * 16 + quad * 4 + reg;
          const int k = nt * 16 + mcol;
          hw[r * 64 + (((k >> 3) ^ (r & 7)) << 3) + (k & 7)] = (_Float16)zv;
        }
  }

  // ---- head: out = z @ W2^T + b2 ----
  {
    half8 zh[2][2];
    read_afrags(hw, quad, mcol, zh);

    const float b2r = (mcol < 13) ? b2v[mcol] : 0.f;
    f32x4 oacc[2];
#pragma unroll
    for (int mt = 0; mt < 2; ++mt) {
      f32x4 z = {b2r, b2r, b2r, b2r};
      oacc[mt] = z;
    }
#pragma unroll
    for (int kt = 0; kt < 2; ++kt) {
      const half8 bfr = ((const half8*)w2_g)[kt * 64 + lane];
#pragma unroll
      for (int mt = 0; mt < 2; ++mt)
        oacc[mt] = __builtin_amdgcn_mfma_f32_16x16x32_f16(zh[mt][kt], bfr, oacc[mt], 0, 0, 0);
    }
    if (mcol < 13) {
#pragma unroll
      for (int mt = 0; mt < 2; ++mt)
#pragma unroll
        for (int reg = 0; reg < 4; ++reg) {
          const int row = row0 + mt * 16 + quad * 4 + reg;
          out[row * 13 + mcol] = oacc[mt][reg];
        }
    }
  }
}

extern "C" void kernel_launch(void* const* d_in, const int* in_sizes, int n_in,
                              void* d_out, int out_size, void* d_ws, size_t ws_size,
                              hipStream_t stream) {
  const float* x    = (const float*)d_in[0];
  const float* W_ih = (const float*)d_in[1];
  const float* W_hh = (const float*)d_in[2];
  const float* b_ih = (const float*)d_in[3];
  const float* b_hh = (const float*)d_in[4];
  const float* W1   = (const float*)d_in[5];
  const float* b1   = (const float*)d_in[6];
  const float* W2   = (const float*)d_in[7];
  const float* b2   = (const float*)d_in[8];
  float* out = (float*)d_out;
  char* ws = (char*)d_ws;

  _Float16* whh = (_Float16*)(ws + WHH_OFF);
  _Float16* wih = (_Float16*)(ws + WIH_OFF);
  _Float16* w1  = (_Float16*)(ws + W1_OFF);
  _Float16* w2  = (_Float16*)(ws + W2_OFF);
  float* bias   = (float*)(ws + BIAS_OFF);

  hipLaunchKernelGGL(prep_kernel, dim3(64), dim3(256), 0, stream,
                     W_ih, W_hh, b_ih, b_hh, W1, W2, whh, wih, w1, w2, bias);

  const int B = in_sizes[0] / (TT * NI);  // 262144
  hipLaunchKernelGGL(lstm_mfma, dim3(B / 128), dim3(256), 0, stream,
                     x, whh, wih, w1, w2, bias, b1, b2, out);
}